// Round 5
// baseline (1148.003 us; speedup 1.0000x reference)
//
#include <hip/hip_runtime.h>
#include <math.h>

// Mamba2: D_MODEL=1024, EXPAND=2, HEADDIM=64, NGROUPS=1, D_STATE=64,
// D_CONV=4, CHUNK=64, B=4, L=4096.  Per-batch pipeline, bf16 activations.
#define BATCH  4
#define LSEQ   4096
#define DMODEL 1024
#define DINNER 2048
#define NH     32
#define HD     64
#define DSTATE 64
#define CONVD  2176      // D_INNER + 2*D_STATE
#define NPROJ  4352      // 34*128: z(2048) | xBC(2176) | dt(32)+pad
#define ZROW   4224      // row stride of zxbc buffer: z(2048) | xBC(2176)
#define NCHUNK 64

typedef __attribute__((ext_vector_type(8))) short bf16x8;
typedef __attribute__((ext_vector_type(4))) float f32x4;

__device__ __forceinline__ float sigm(float x){ return 1.f/(1.f+expf(-x)); }

__device__ __forceinline__ unsigned short f2bf(float x){
    unsigned u = __float_as_uint(x);
    unsigned r = (u + 0x7fffu + ((u>>16)&1u)) >> 16;
    return (unsigned short)r;
}
__device__ __forceinline__ float bf2f(unsigned short h){
    return __uint_as_float(((unsigned)h)<<16);
}

// async global (16B/lane) -> LDS (wave-uniform base + lane*16)
__device__ __forceinline__ void gl2lds16(const unsigned short* g, short* l){
    __builtin_amdgcn_global_load_lds(
        (const __attribute__((address_space(1))) unsigned int*)g,
        (__attribute__((address_space(3))) unsigned int*)l, 16, 0, 0);
}

// ---------------------------------------------------------------------------
// f32 -> bf16 streaming convert (n multiple of 8)
// ---------------------------------------------------------------------------
__global__ __launch_bounds__(256)
void f32_to_bf16(const float* __restrict__ in, unsigned short* __restrict__ o, size_t n)
{
    size_t i = ((size_t)blockIdx.x*256 + threadIdx.x)*8;
    if (i >= n) return;
    float4 a = *(const float4*)(in + i);
    float4 b = *(const float4*)(in + i + 4);
    uint4 v;
    v.x = (unsigned)f2bf(a.x) | ((unsigned)f2bf(a.y)<<16);
    v.y = (unsigned)f2bf(a.z) | ((unsigned)f2bf(a.w)<<16);
    v.z = (unsigned)f2bf(b.x) | ((unsigned)f2bf(b.y)<<16);
    v.w = (unsigned)f2bf(b.z) | ((unsigned)f2bf(b.w)<<16);
    *(uint4*)(o + i) = v;
}

// ---------------------------------------------------------------------------
// bf16 MFMA GEMM NT, 128x128 tile, BK=32, 4 waves, 4x4 x mfma 16x16x32.
// AF32: A is fp32, staged via VALU convert + ds_write (B stays async).
// EPI=0: fp32 store to Cf (ldc).  EPI=1: merged in_proj epilogue:
//   tiles 0..15 -> z bf16 into zxbc, 16..32 -> xBC bf16 + conv halo,
//   tile 33 -> softplus dt fp32.  (B must have >= gridDim.x*128 rows.)
// ---------------------------------------------------------------------------
template<int EPI, bool AF32>
__global__ __launch_bounds__(256)
void gemm_mfma(const void* __restrict__ Av,
               const unsigned short* __restrict__ B,
               int K, int lda, int ldc,
               float* __restrict__ Cf,
               unsigned short* __restrict__ zxbc,
               float* __restrict__ dtout,
               const float* __restrict__ dt_bias,
               unsigned short* __restrict__ halo)
{
    __shared__ short As[128*32];
    __shared__ short Bs[128*32];
    const int tid  = threadIdx.x;
    const int wave = tid >> 6;
    const int lane = tid & 63;
    const int bm = blockIdx.y * 128;
    const int bn = blockIdx.x * 128;
    const int wr = (wave >> 1) * 64;
    const int wc = (wave & 1) * 64;
    const int quad = lane >> 4;
    const int l15  = lane & 15;

    f32x4 acc[4][4];
    #pragma unroll
    for (int i=0;i<4;i++)
        #pragma unroll
        for (int j=0;j<4;j++)
            acc[i][j] = (f32x4){0.f,0.f,0.f,0.f};

    const int srow = (lane >> 2);
    const int skc  = (lane & 3) * 8;

    for (int k0 = 0; k0 < K; k0 += 32){
        if (AF32){
            const float* A = (const float*)Av;
            #pragma unroll
            for (int it=0; it<4; it++){
                int idx = tid + it*256;
                int row = idx >> 3;          // 0..127
                int c4  = (idx & 7) * 4;     // 0,4,..,28
                float4 v = *(const float4*)(A + (size_t)(bm+row)*lda + k0 + c4);
                ushort4 h4;
                h4.x = f2bf(v.x); h4.y = f2bf(v.y); h4.z = f2bf(v.z); h4.w = f2bf(v.w);
                *(ushort4*)&As[row*32 + c4] = h4;
            }
            #pragma unroll
            for (int s=0; s<2; s++){
                int t = wave*2 + s;          // 0..7
                int r = t*16 + srow;
                gl2lds16(B + (size_t)(bn + r)*K + k0 + skc, &Bs[t*512]);
            }
        } else {
            const unsigned short* A = (const unsigned short*)Av;
            #pragma unroll
            for (int s=0; s<4; s++){
                int t = wave*4 + s;
                int r = (t & 7)*16 + srow;
                if (t < 8)
                    gl2lds16(A + (size_t)(bm + r)*lda + k0 + skc, &As[(t & 7)*512]);
                else
                    gl2lds16(B + (size_t)(bn + r)*K + k0 + skc, &Bs[(t & 7)*512]);
            }
        }
        __syncthreads();
        bf16x8 af[4], bg[4];
        #pragma unroll
        for (int i=0;i<4;i++)
            af[i] = *(const bf16x8*)&As[(wr + i*16 + l15)*32 + quad*8];
        #pragma unroll
        for (int j=0;j<4;j++)
            bg[j] = *(const bf16x8*)&Bs[(wc + j*16 + l15)*32 + quad*8];
        #pragma unroll
        for (int i=0;i<4;i++)
            #pragma unroll
            for (int j=0;j<4;j++)
                acc[i][j] = __builtin_amdgcn_mfma_f32_16x16x32_bf16(af[i], bg[j], acc[i][j], 0,0,0);
        __syncthreads();
    }

    // C/D layout: col = lane&15, row = quad*4 + reg   [m89-verified]
    if (EPI == 0){
        #pragma unroll
        for (int i=0;i<4;i++)
            #pragma unroll
            for (int j=0;j<4;j++){
                int col = bn + wc + j*16 + l15;
                #pragma unroll
                for (int r=0;r<4;r++){
                    int row = bm + wr + i*16 + quad*4 + r;
                    Cf[(size_t)row*ldc + col] = acc[i][j][r];
                }
            }
    } else {
        if (bn < DINNER){
            // z columns -> zxbc cols 0..2047 (bf16)
            #pragma unroll
            for (int i=0;i<4;i++)
                #pragma unroll
                for (int r=0;r<4;r++){
                    int row = bm + wr + i*16 + quad*4 + r;
                    #pragma unroll
                    for (int j=0;j<4;j++){
                        int col = bn + wc + j*16 + l15;
                        zxbc[(size_t)row*ZROW + col] = f2bf(acc[i][j][r]);
                    }
                }
        } else if (bn < DINNER + CONVD){
            // xBC columns -> zxbc cols 2048..4223 (bf16) + pre-conv halo
            #pragma unroll
            for (int i=0;i<4;i++)
                #pragma unroll
                for (int r=0;r<4;r++){
                    int row = bm + wr + i*16 + quad*4 + r;
                    int rel = row & 63;
                    int seg = (row >> 6) + 1;
                    #pragma unroll
                    for (int j=0;j<4;j++){
                        int col = bn + wc + j*16 + l15;
                        unsigned short v = f2bf(acc[i][j][r]);
                        zxbc[(size_t)row*ZROW + col] = v;
                        if (rel >= 61 && seg < NCHUNK)
                            halo[((size_t)(seg*3 + (rel-61)))*CONVD + (col - DINNER)] = v;
                    }
                }
        } else if (wc == 0){
            // dt tile (bn == 4224): h = j*16 + l15 for j<2
            #pragma unroll
            for (int j=0;j<2;j++){
                int h = j*16 + l15;
                #pragma unroll
                for (int i=0;i<4;i++)
                    #pragma unroll
                    for (int r=0;r<4;r++){
                        int row = bm + wr + i*16 + quad*4 + r;
                        float t = acc[i][j][r] + dt_bias[h];
                        dtout[(size_t)row*NH + h] = (t > 20.f) ? t : log1pf(expf(t));
                    }
            }
        }
    }
}

// ---------------------------------------------------------------------------
// Causal depthwise conv(4) + bias + SiLU, in place over bf16 xBC region.
// ---------------------------------------------------------------------------
__global__ __launch_bounds__(256)
void conv_inplace(unsigned short* __restrict__ zxbc,
                  const unsigned short* __restrict__ halo,
                  const float* __restrict__ conv_w, const float* __restrict__ conv_b)
{
    int c = blockIdx.x*256 + threadIdx.x;
    if (c >= CONVD) return;
    int seg = blockIdx.y;
    const float w0=conv_w[c*4+0], w1=conv_w[c*4+1], w2=conv_w[c*4+2], w3=conv_w[c*4+3];
    const float bias = conv_b[c];
    float x0=0.f, x1=0.f, x2=0.f;
    if (seg > 0){
        const unsigned short* hp = halo + (size_t)(seg*3)*CONVD + c;
        x0 = bf2f(hp[0]); x1 = bf2f(hp[CONVD]); x2 = bf2f(hp[2*CONVD]);
    }
    unsigned short* p = zxbc + (size_t)(seg*64)*ZROW + DINNER + c;
    for (int i=0;i<64;i++){
        float x3 = bf2f(*p);
        float v = fmaf(w0,x0,fmaf(w1,x1,fmaf(w2,x2,fmaf(w3,x3,bias))));
        *p = f2bf(v * sigm(v));
        x0=x1; x1=x2; x2=x3; p += ZROW;
    }
}

// ---------------------------------------------------------------------------
// states_intra: per (c,h).  loc_state[p][n] = sum_l x[l][p]*dt[l]*dec[l]*B[l][n]
// via NT MFMA on transposed bf16 LDS tiles.  Also writes acs + csum.
// ---------------------------------------------------------------------------
__global__ __launch_bounds__(256)
void states_intra(const unsigned short* __restrict__ zxbc,
                  const float* __restrict__ dtbuf,
                  const float* __restrict__ A_log,
                  unsigned short* __restrict__ locst,
                  float* __restrict__ acsbuf,
                  float* __restrict__ csumbuf)
{
    const int c = blockIdx.x, h = blockIdx.y;
    __shared__ unsigned short XT[64*72];   // XT[p][l] = x[l][p] (raw)
    __shared__ unsigned short BT[64*72];   // BT[n][l] = B[l][n]*dec[l]*dt[l]
    __shared__ float dt_sh[64], acs_sh[64], w_sh[64];
    const int tid = threadIdx.x;
    const size_t row0 = (size_t)(c*64)*ZROW;

    if (tid < 64) dt_sh[tid] = dtbuf[(size_t)(c*64+tid)*NH + h];
    __syncthreads();
    if (tid == 0){
        float Ah = -expf(A_log[h]); float s = 0.f;
        for (int l=0;l<64;l++){ s = fmaf(Ah, dt_sh[l], s); acs_sh[l] = s; }
    }
    __syncthreads();
    const float a63 = acs_sh[63];
    if (tid < 64){
        float a = acs_sh[tid];
        acsbuf[((size_t)h*64 + c)*64 + tid] = a;
        w_sh[tid] = expf(a63 - a) * dt_sh[tid];
    }
    if (tid == 0) csumbuf[(size_t)h*64 + c] = a63;
    __syncthreads();

    {   // stage transposed tiles from bf16 rows
        const int l  = tid >> 2;
        const int f4 = tid & 3;
        const unsigned short* xr = zxbc + row0 + (size_t)l*ZROW;
        const float w = w_sh[l];
        #pragma unroll
        for (int q=0;q<4;q++){
            int col = f4*4 + q*16;
            uint2 xv = *(const uint2*)(xr + DINNER + h*HD + col);
            uint2 bv = *(const uint2*)(xr + DINNER + DINNER + col);
            XT[(col+0)*72 + l] = (unsigned short)(xv.x & 0xffff);
            XT[(col+1)*72 + l] = (unsigned short)(xv.x >> 16);
            XT[(col+2)*72 + l] = (unsigned short)(xv.y & 0xffff);
            XT[(col+3)*72 + l] = (unsigned short)(xv.y >> 16);
            BT[(col+0)*72 + l] = f2bf(bf2f((unsigned short)(bv.x & 0xffff))*w);
            BT[(col+1)*72 + l] = f2bf(bf2f((unsigned short)(bv.x >> 16))*w);
            BT[(col+2)*72 + l] = f2bf(bf2f((unsigned short)(bv.y & 0xffff))*w);
            BT[(col+3)*72 + l] = f2bf(bf2f((unsigned short)(bv.y >> 16))*w);
        }
    }
    __syncthreads();

    const int wave = tid >> 6, lane = tid & 63;
    const int quad = lane >> 4, l15 = lane & 15;
    f32x4 acc[4];
    #pragma unroll
    for (int j=0;j<4;j++) acc[j] = (f32x4){0.f,0.f,0.f,0.f};
    #pragma unroll
    for (int ks=0;ks<2;ks++){
        bf16x8 af = *(const bf16x8*)&XT[(wave*16 + l15)*72 + ks*32 + quad*8];
        #pragma unroll
        for (int j=0;j<4;j++){
            bf16x8 bf = *(const bf16x8*)&BT[(j*16 + l15)*72 + ks*32 + quad*8];
            acc[j] = __builtin_amdgcn_mfma_f32_16x16x32_bf16(af, bf, acc[j], 0,0,0);
        }
    }
    const size_t sbase = ((size_t)c*NH + h)*4096;
    #pragma unroll
    for (int j=0;j<4;j++)
        #pragma unroll
        for (int r=0;r<4;r++){
            int p = wave*16 + quad*4 + r;
            int n = j*16 + l15;
            locst[sbase + (size_t)p*64 + n] = f2bf(acc[j][r]);
        }
}

// ---------------------------------------------------------------------------
// Inter-chunk scan, in place (loc -> entering), grid (NH,2).
// ---------------------------------------------------------------------------
__global__ __launch_bounds__(256)
void chunk_scan(unsigned short* __restrict__ states,
                const float* __restrict__ csumbuf,
                const float* __restrict__ init_states)
{
    const int h = blockIdx.x, half = blockIdx.y;
    __shared__ float cs_sh[64];
    const int tid = threadIdx.x;
    if (tid < 64) cs_sh[tid] = csumbuf[(size_t)h*64 + tid];
    __syncthreads();
    const int e0 = half*2048 + tid*8;
    float S[8];
    {
        const float4* ip = (const float4*)(init_states + (size_t)h*4096 + e0);
        float4 v0 = ip[0], v1 = ip[1];
        S[0]=v0.x; S[1]=v0.y; S[2]=v0.z; S[3]=v0.w;
        S[4]=v1.x; S[5]=v1.y; S[6]=v1.z; S[7]=v1.w;
    }
    for (int zg=0; zg<8; zg++){
        uint4 L[8];
        #pragma unroll
        for (int k=0;k<8;k++)
            L[k] = *(const uint4*)(states + ((size_t)(zg*8+k)*NH + h)*4096 + e0);
        #pragma unroll
        for (int k=0;k<8;k++){
            int z = zg*8 + k;
            float dec = expf(cs_sh[z]);
            uint4 o;
            o.x = (unsigned)f2bf(S[0]) | ((unsigned)f2bf(S[1])<<16);
            o.y = (unsigned)f2bf(S[2]) | ((unsigned)f2bf(S[3])<<16);
            o.z = (unsigned)f2bf(S[4]) | ((unsigned)f2bf(S[5])<<16);
            o.w = (unsigned)f2bf(S[6]) | ((unsigned)f2bf(S[7])<<16);
            *(uint4*)(states + ((size_t)z*NH + h)*4096 + e0) = o;
            unsigned a[4] = {L[k].x, L[k].y, L[k].z, L[k].w};
            #pragma unroll
            for (int q=0;q<4;q++){
                float lo = bf2f((unsigned short)(a[q]&0xffff));
                float hi = bf2f((unsigned short)(a[q]>>16));
                S[q*2+0] = fmaf(dec, S[q*2+0], lo);
                S[q*2+1] = fmaf(dec, S[q*2+1], hi);
            }
        }
    }
}

// ---------------------------------------------------------------------------
// y_fused: per (c,h).  G = C·B^T (MFMA) -> score (mask/decay/dt + D on diag)
// -> Y = score·x + (ea·C)·S_enter^T, single bf16 write over x region.
// ---------------------------------------------------------------------------
__global__ __launch_bounds__(256)
void y_fused(unsigned short* __restrict__ zxbc,
             const float* __restrict__ dtbuf,
             const unsigned short* __restrict__ entst,
             const float* __restrict__ acsbuf,
             const float* __restrict__ Dvec)
{
    const int c = blockIdx.x, h = blockIdx.y;
    __shared__ unsigned short Cr[64*72];   // C raw
    __shared__ unsigned short Ce[64*72];   // C * ea[l]
    __shared__ unsigned short Bm[64*72];   // B raw; reused for score
    __shared__ unsigned short XT[64*72];   // x^T
    __shared__ unsigned short Sv[64*72];   // entering states [p][n]
    __shared__ float acs_sh[64], dt_sh[64], ea_sh[64];
    const int tid = threadIdx.x;
    const size_t row0 = (size_t)(c*64)*ZROW;
    const size_t sbase = ((size_t)c*NH + h)*4096;

    if (tid < 64){
        float a = acsbuf[((size_t)h*64 + c)*64 + tid];
        acs_sh[tid] = a;
        ea_sh[tid]  = expf(a);
        dt_sh[tid]  = dtbuf[(size_t)(c*64 + tid)*NH + h];
    }
    __syncthreads();

    {   // stage tiles
        const int l  = tid >> 2;
        const int f4 = tid & 3;
        const unsigned short* xr = zxbc + row0 + (size_t)l*ZROW;
        const float el = ea_sh[l];
        #pragma unroll
        for (int q=0;q<4;q++){
            int col = f4*4 + q*16;
            uint2 cv = *(const uint2*)(xr + DINNER + DINNER + DSTATE + col);
            uint2 bv = *(const uint2*)(xr + DINNER + DINNER + col);
            uint2 xv = *(const uint2*)(xr + DINNER + h*HD + col);
            *(uint2*)&Cr[l*72 + col] = cv;
            *(uint2*)&Bm[l*72 + col] = bv;
            unsigned short* ce = &Ce[l*72 + col];
            ce[0] = f2bf(bf2f((unsigned short)(cv.x & 0xffff))*el);
            ce[1] = f2bf(bf2f((unsigned short)(cv.x >> 16))*el);
            ce[2] = f2bf(bf2f((unsigned short)(cv.y & 0xffff))*el);
            ce[3] = f2bf(bf2f((unsigned short)(cv.y >> 16))*el);
            XT[(col+0)*72 + l] = (unsigned short)(xv.x & 0xffff);
            XT[(col+1)*72 + l] = (unsigned short)(xv.x >> 16);
            XT[(col+2)*72 + l] = (unsigned short)(xv.y & 0xffff);
            XT[(col+3)*72 + l] = (unsigned short)(xv.y >> 16);
            *(uint2*)&Sv[l*72 + col] = *(const uint2*)(entst + sbase + (size_t)l*64 + col);
        }
    }
    __syncthreads();

    const int wave = tid >> 6, lane = tid & 63;
    const int quad = lane >> 4, l15 = lane & 15;

    // G[l][s] = sum_n C[l][n] * B[s][n]
    f32x4 g[4];
    #pragma unroll
    for (int j=0;j<4;j++) g[j] = (f32x4){0.f,0.f,0.f,0.f};
    #pragma unroll
    for (int ks=0;ks<2;ks++){
        bf16x8 af = *(const bf16x8*)&Cr[(wave*16 + l15)*72 + ks*32 + quad*8];
        #pragma unroll
        for (int j=0;j<4;j++){
            bf16x8 bf = *(const bf16x8*)&Bm[(j*16 + l15)*72 + ks*32 + quad*8];
            g[j] = __builtin_amdgcn_mfma_f32_16x16x32_bf16(af, bf, g[j], 0,0,0);
        }
    }
    __syncthreads();   // all Bm reads done before overwrite with score

    // score[l][s] = (s<=l) ? G*exp(acs[l]-acs[s])*dt[s] : 0 ; +D on diagonal
    const float Dh = Dvec[h];
    #pragma unroll
    for (int j=0;j<4;j++)
        #pragma unroll
        for (int r=0;r<4;r++){
            int l = wave*16 + quad*4 + r;
            int s = j*16 + l15;
            float v = (s <= l) ? g[j][r]*expf(acs_sh[l]-acs_sh[s])*dt_sh[s] : 0.f;
            if (s == l) v += Dh;
            Bm[l*72 + s] = f2bf(v);
        }
    __syncthreads();

    // Y[l][p] = sum_s score[l][s]*x[s][p] + sum_n eaC[l][n]*S[p][n]
    f32x4 y[4];
    #pragma unroll
    for (int j=0;j<4;j++) y[j] = (f32x4){0.f,0.f,0.f,0.f};
    #pragma unroll
    for (int ks=0;ks<2;ks++){
        bf16x8 a1 = *(const bf16x8*)&Bm[(wave*16 + l15)*72 + ks*32 + quad*8];
        bf16x8 a2 = *(const bf16x8*)&Ce[(wave*16 + l15)*72 + ks*32 + quad*8];
        #pragma unroll
        for (int j=0;j<4;j++){
            bf16x8 b1 = *(const bf16x8*)&XT[(j*16 + l15)*72 + ks*32 + quad*8];
            bf16x8 b2 = *(const bf16x8*)&Sv[(j*16 + l15)*72 + ks*32 + quad*8];
            y[j] = __builtin_amdgcn_mfma_f32_16x16x32_bf16(a1, b1, y[j], 0,0,0);
            y[j] = __builtin_amdgcn_mfma_f32_16x16x32_bf16(a2, b2, y[j], 0,0,0);
        }
    }

    // single bf16 write over x region
    #pragma unroll
    for (int j=0;j<4;j++)
        #pragma unroll
        for (int r=0;r<4;r++){
            int l = wave*16 + quad*4 + r;
            int p = j*16 + l15;
            zxbc[row0 + (size_t)l*ZROW + DINNER + h*HD + p] = f2bf(y[j][r]);
        }
}

// ---------------------------------------------------------------------------
// gate + RMSNorm: y = RMSNorm(Y*silu(z))*w; z cols 0..2047, Y cols 2048..4095
// of the same zxbc row; writes y bf16 over z cols.
// ---------------------------------------------------------------------------
__global__ __launch_bounds__(256)
void gate_norm(unsigned short* __restrict__ zxbc, const float* __restrict__ norm_w)
{
    const int m = blockIdx.x;
    const int tid = threadIdx.x;
    unsigned short* row = zxbc + (size_t)m*ZROW;
    uint4 zv = *(const uint4*)(row + tid*8);
    uint4 yv = *(const uint4*)(row + DINNER + tid*8);
    unsigned zz[4] = {zv.x, zv.y, zv.z, zv.w};
    unsigned yy[4] = {yv.x, yv.y, yv.z, yv.w};
    float g[8];
    float acc = 0.f;
    #pragma unroll
    for (int q=0;q<4;q++){
        float zl = bf2f((unsigned short)(zz[q]&0xffff));
        float zh = bf2f((unsigned short)(zz[q]>>16));
        float yl = bf2f((unsigned short)(yy[q]&0xffff));
        float yh = bf2f((unsigned short)(yy[q]>>16));
        g[q*2+0] = yl * zl * sigm(zl);
        g[q*2+1] = yh * zh * sigm(zh);
        acc += g[q*2]*g[q*2] + g[q*2+1]*g[q*2+1];
    }
    #pragma unroll
    for (int o=32;o>0;o>>=1) acc += __shfl_down(acc, o, 64);
    __shared__ float red[4];
    if ((tid & 63)==0) red[tid>>6] = acc;
    __syncthreads();
    float tot = red[0]+red[1]+red[2]+red[3];
    float scale = rsqrtf(tot * (1.f/2048.f) + 1e-5f);
    const float* nw = norm_w + tid*8;
    float4 w0 = *(const float4*)nw;
    float4 w1 = *(const float4*)(nw+4);
    float Wv[8] = {w0.x,w0.y,w0.z,w0.w,w1.x,w1.y,w1.z,w1.w};
    uint4 ov;
    unsigned ow[4];
    #pragma unroll
    for (int q=0;q<4;q++){
        unsigned short lo = f2bf(g[q*2+0]*scale*Wv[q*2+0]);
        unsigned short hi = f2bf(g[q*2+1]*scale*Wv[q*2+1]);
        ow[q] = (unsigned)lo | ((unsigned)hi<<16);
    }
    ov.x=ow[0]; ov.y=ow[1]; ov.z=ow[2]; ov.w=ow[3];
    *(uint4*)(row + tid*8) = ov;
}

// ---------------------------------------------------------------------------
extern "C" void kernel_launch(void* const* d_in, const int* in_sizes, int n_in,
                              void* d_out, int out_size, void* d_ws, size_t ws_size,
                              hipStream_t stream) {
    const float* u           = (const float*)d_in[0];
    const float* in_proj_w   = (const float*)d_in[1];
    const float* conv_w      = (const float*)d_in[2];
    const float* conv_b      = (const float*)d_in[3];
    const float* init_states = (const float*)d_in[4];
    const float* dt_bias     = (const float*)d_in[5];
    const float* A_log       = (const float*)d_in[6];
    const float* Dv          = (const float*)d_in[7];
    const float* norm_w      = (const float*)d_in[8];
    const float* out_proj_w  = (const float*)d_in[9];
    float* out = (float*)d_out;

    // Workspace (65.86 MB total, under proven 71.74 MB envelope):
    //  zxbc   bf16 4096x4224 = 34,603,008
    //  states bf16           = 16,777,216
    //  wibf   bf16 4352x1024 =  8,912,896  (padded to 34 N-tiles)
    //  woutbf bf16 1024x2048 =  4,194,304
    //  dtbuf  fp32           =    524,288
    //  halo bf16 / acs fp32  =    835,584  (union; disjoint lifetimes)
    //  csum   fp32           =      8,192
    char* wsb = (char*)d_ws;
    unsigned short* zxbc    = (unsigned short*)(wsb);
    unsigned short* statesz = (unsigned short*)(wsb + 34603008);
    unsigned short* wibf    = (unsigned short*)(wsb + 34603008 + 16777216);
    unsigned short* woutbf  = (unsigned short*)(wsb + 34603008 + 16777216 + 8912896);
    float*          dtbuf   = (float*)(wsb + 34603008 + 16777216 + 8912896 + 4194304);
    char*           haloacs = (wsb + 34603008 + 16777216 + 8912896 + 4194304 + 524288);
    float*          csumbuf = (float*)(wsb + 34603008 + 16777216 + 8912896 + 4194304 + 524288 + 835584);
    unsigned short* halo    = (unsigned short*)haloacs;  // phases 1-2
    float*          acsbuf  = (float*)haloacs;           // phases 3-5

    // weights -> bf16 (once)
    f32_to_bf16<<<dim3((4256*1024/8 + 255)/256), 256, 0, stream>>>(
        in_proj_w, wibf, (size_t)4256*1024);
    f32_to_bf16<<<dim3(1024*2048/8/256), 256, 0, stream>>>(
        out_proj_w, woutbf, (size_t)1024*2048);

    for (int b=0; b<BATCH; b++){
        const float* ub   = u   + (size_t)b*LSEQ*DMODEL;
        float*       outb = out + (size_t)b*LSEQ*DMODEL;

        // 1) merged in_proj (z + xBC + dt), fp32 A staged in-kernel
        gemm_mfma<1,true><<<dim3(NPROJ/128, LSEQ/128), 256, 0, stream>>>(
            ub, wibf, DMODEL, DMODEL, 0,
            nullptr, zxbc, dtbuf, dt_bias, halo);
        // 2) causal conv + silu in place (bf16)
        conv_inplace<<<dim3((CONVD+255)/256, NCHUNK), 256, 0, stream>>>(
            zxbc, halo, conv_w, conv_b);
        // 3) local states (MFMA) + acs/csum
        states_intra<<<dim3(NCHUNK, NH), 256, 0, stream>>>(
            zxbc, dtbuf, A_log, statesz, acsbuf, csumbuf);
        // 4) inter-chunk scan in place (loc -> entering)
        chunk_scan<<<dim3(NH, 2), 256, 0, stream>>>(statesz, csumbuf, init_states);
        // 5) fused Y = Y_diag + Y_off + x*D (D folded into score diagonal)
        y_fused<<<dim3(NCHUNK, NH), 256, 0, stream>>>(
            zxbc, dtbuf, statesz, acsbuf, Dv);
        // 6) gate + RMSNorm -> y bf16 over z cols
        gate_norm<<<dim3(LSEQ), 256, 0, stream>>>(zxbc, norm_w);
        // 7) out_proj -> out fp32  (A = y in zxbc, lda=ZROW)
        gemm_mfma<0,false><<<dim3(DMODEL/128, LSEQ/128), 256, 0, stream>>>(
            zxbc, woutbf, DINNER, ZROW, DMODEL,
            outb, nullptr, nullptr, nullptr, nullptr);
    }
}

// Round 6
// 661.646 us; speedup vs baseline: 1.7351x; 1.7351x over previous
//
#include <hip/hip_runtime.h>
#include <math.h>

// Mamba2: D_MODEL=1024, EXPAND=2, HEADDIM=64, NGROUPS=1, D_STATE=64,
// D_CONV=4, CHUNK=64, B=4, L=4096.
// Runtime-adaptive: fully-batched pipeline if ws_size allows (~226 MB),
// else per-batch windowed pipeline (~66 MB).  Same kernels in both modes.
#define BATCH  4
#define LSEQ   4096
#define DMODEL 1024
#define DINNER 2048
#define NH     32
#define HD     64
#define DSTATE 64
#define CONVD  2176      // D_INNER + 2*D_STATE
#define NPROJ  4352      // 34*128: z(2048) | xBC(2176) | dt(32)+pad
#define ZROW   4224      // zxbc row stride: z(2048) | xBC(2176)
#define NCHUNK 64

typedef __attribute__((ext_vector_type(8))) short bf16x8;
typedef __attribute__((ext_vector_type(4))) float f32x4;

__device__ __forceinline__ float sigm(float x){ return 1.f/(1.f+expf(-x)); }

__device__ __forceinline__ unsigned short f2bf(float x){
    unsigned u = __float_as_uint(x);
    unsigned r = (u + 0x7fffu + ((u>>16)&1u)) >> 16;
    return (unsigned short)r;
}
__device__ __forceinline__ float bf2f(unsigned short h){
    return __uint_as_float(((unsigned)h)<<16);
}

// async global (16B/lane) -> LDS (wave-uniform base + lane*16)
__device__ __forceinline__ void gl2lds16(const unsigned short* g, short* l){
    __builtin_amdgcn_global_load_lds(
        (const __attribute__((address_space(1))) unsigned int*)g,
        (__attribute__((address_space(3))) unsigned int*)l, 16, 0, 0);
}

// ---------------------------------------------------------------------------
// f32 -> bf16 streaming convert (n multiple of 8)
// ---------------------------------------------------------------------------
__global__ __launch_bounds__(256)
void f32_to_bf16(const float* __restrict__ in, unsigned short* __restrict__ o, size_t n)
{
    size_t i = ((size_t)blockIdx.x*256 + threadIdx.x)*8;
    if (i >= n) return;
    float4 a = *(const float4*)(in + i);
    float4 b = *(const float4*)(in + i + 4);
    uint4 v;
    v.x = (unsigned)f2bf(a.x) | ((unsigned)f2bf(a.y)<<16);
    v.y = (unsigned)f2bf(a.z) | ((unsigned)f2bf(a.w)<<16);
    v.z = (unsigned)f2bf(b.x) | ((unsigned)f2bf(b.y)<<16);
    v.w = (unsigned)f2bf(b.z) | ((unsigned)f2bf(b.w)<<16);
    *(uint4*)(o + i) = v;
}

// ---------------------------------------------------------------------------
// bf16 MFMA GEMM NT, 128x128 tile, BK=32, 4 waves, 4x4 x mfma 16x16x32.
// All-async global->LDS staging (A row stride lda, B row stride K).
// EPI=0: fp32 store to Cf (ldc).  EPI=1: merged in_proj epilogue:
//   tiles 0..15 -> z bf16 into zxbc, 16..32 -> xBC bf16 + conv halo,
//   tile 33 -> softplus dt fp32.  M (rows) = gridDim.y*128, window-local.
// ---------------------------------------------------------------------------
template<int EPI>
__global__ __launch_bounds__(256)
void gemm_mfma(const unsigned short* __restrict__ A,
               const unsigned short* __restrict__ B,
               int K, int lda, int ldc,
               float* __restrict__ Cf,
               unsigned short* __restrict__ zxbc,
               float* __restrict__ dtout,
               const float* __restrict__ dt_bias,
               unsigned short* __restrict__ halo)
{
    __shared__ short As[128*32];
    __shared__ short Bs[128*32];
    const int tid  = threadIdx.x;
    const int wave = tid >> 6;
    const int lane = tid & 63;
    const int bm = blockIdx.y * 128;
    const int bn = blockIdx.x * 128;
    const int wr = (wave >> 1) * 64;
    const int wc = (wave & 1) * 64;
    const int quad = lane >> 4;
    const int l15  = lane & 15;

    f32x4 acc[4][4];
    #pragma unroll
    for (int i=0;i<4;i++)
        #pragma unroll
        for (int j=0;j<4;j++)
            acc[i][j] = (f32x4){0.f,0.f,0.f,0.f};

    const int srow = (lane >> 2);
    const int skc  = (lane & 3) * 8;

    for (int k0 = 0; k0 < K; k0 += 32){
        #pragma unroll
        for (int s=0; s<4; s++){
            int t = wave*4 + s;
            int r = (t & 7)*16 + srow;
            if (t < 8)
                gl2lds16(A + (size_t)(bm + r)*lda + k0 + skc, &As[(t & 7)*512]);
            else
                gl2lds16(B + (size_t)(bn + r)*K + k0 + skc, &Bs[(t & 7)*512]);
        }
        __syncthreads();
        bf16x8 af[4], bg[4];
        #pragma unroll
        for (int i=0;i<4;i++)
            af[i] = *(const bf16x8*)&As[(wr + i*16 + l15)*32 + quad*8];
        #pragma unroll
        for (int j=0;j<4;j++)
            bg[j] = *(const bf16x8*)&Bs[(wc + j*16 + l15)*32 + quad*8];
        #pragma unroll
        for (int i=0;i<4;i++)
            #pragma unroll
            for (int j=0;j<4;j++)
                acc[i][j] = __builtin_amdgcn_mfma_f32_16x16x32_bf16(af[i], bg[j], acc[i][j], 0,0,0);
        __syncthreads();
    }

    // C/D layout: col = lane&15, row = quad*4 + reg   [m89-verified]
    if (EPI == 0){
        #pragma unroll
        for (int i=0;i<4;i++)
            #pragma unroll
            for (int j=0;j<4;j++){
                int col = bn + wc + j*16 + l15;
                #pragma unroll
                for (int r=0;r<4;r++){
                    int row = bm + wr + i*16 + quad*4 + r;
                    Cf[(size_t)row*ldc + col] = acc[i][j][r];
                }
            }
    } else {
        const int Mrows = gridDim.y * 128;
        if (bn < DINNER){
            #pragma unroll
            for (int i=0;i<4;i++)
                #pragma unroll
                for (int r=0;r<4;r++){
                    int row = bm + wr + i*16 + quad*4 + r;
                    #pragma unroll
                    for (int j=0;j<4;j++){
                        int col = bn + wc + j*16 + l15;
                        zxbc[(size_t)row*ZROW + col] = f2bf(acc[i][j][r]);
                    }
                }
        } else if (bn < DINNER + CONVD){
            #pragma unroll
            for (int i=0;i<4;i++)
                #pragma unroll
                for (int r=0;r<4;r++){
                    int row = bm + wr + i*16 + quad*4 + r;
                    int rel = row & 63;
                    int seg = (row >> 6) + 1;
                    #pragma unroll
                    for (int j=0;j<4;j++){
                        int col = bn + wc + j*16 + l15;
                        unsigned short v = f2bf(acc[i][j][r]);
                        zxbc[(size_t)row*ZROW + col] = v;
                        if (rel >= 61 && seg*64 < Mrows)
                            halo[((size_t)(seg*3 + (rel-61)))*CONVD + (col - DINNER)] = v;
                    }
                }
        } else if (wc == 0){
            #pragma unroll
            for (int j=0;j<2;j++){
                int h = j*16 + l15;
                #pragma unroll
                for (int i=0;i<4;i++)
                    #pragma unroll
                    for (int r=0;r<4;r++){
                        int row = bm + wr + i*16 + quad*4 + r;
                        float t = acc[i][j][r] + dt_bias[h];
                        dtout[(size_t)row*NH + h] = (t > 20.f) ? t : log1pf(expf(t));
                    }
            }
        }
    }
}

// ---------------------------------------------------------------------------
// Causal conv(4) + bias + SiLU, in place, bf16.  grid (9, 64*nb); seg is the
// GLOBAL 64-row segment; batch boundaries (seg&63==0) use zero history.
// ---------------------------------------------------------------------------
__global__ __launch_bounds__(256)
void conv_inplace(unsigned short* __restrict__ zxbc,
                  const unsigned short* __restrict__ halo,
                  const float* __restrict__ conv_w, const float* __restrict__ conv_b)
{
    int c = blockIdx.x*256 + threadIdx.x;
    if (c >= CONVD) return;
    int seg = blockIdx.y;
    const float w0=conv_w[c*4+0], w1=conv_w[c*4+1], w2=conv_w[c*4+2], w3=conv_w[c*4+3];
    const float bias = conv_b[c];
    float x0=0.f, x1=0.f, x2=0.f;
    if ((seg & 63) != 0){
        const unsigned short* hp = halo + (size_t)(seg*3)*CONVD + c;
        x0 = bf2f(hp[0]); x1 = bf2f(hp[CONVD]); x2 = bf2f(hp[2*CONVD]);
    }
    unsigned short* p = zxbc + (size_t)(seg*64)*ZROW + DINNER + c;
    for (int i=0;i<64;i++){
        float x3 = bf2f(*p);
        float v = fmaf(w0,x0,fmaf(w1,x1,fmaf(w2,x2,fmaf(w3,x3,bias))));
        *p = f2bf(v * sigm(v));
        x0=x1; x1=x2; x2=x3; p += ZROW;
    }
}

// ---------------------------------------------------------------------------
// states_intra: grid (NH, nchunks) [h fastest -> L2 reuse of B/x rows].
// loc_state[p][n] = sum_l x[l][p]*dt[l]*dec[l]*B[l][n] via NT MFMA.
// acs layout [c][h][l]; csum [c][h]; states [(c*NH+h)].
// ---------------------------------------------------------------------------
__global__ __launch_bounds__(256)
void states_intra(const unsigned short* __restrict__ zxbc,
                  const float* __restrict__ dtbuf,
                  const float* __restrict__ A_log,
                  unsigned short* __restrict__ locst,
                  float* __restrict__ acsbuf,
                  float* __restrict__ csumbuf)
{
    const int h = blockIdx.x, c = blockIdx.y;
    __shared__ unsigned short XT[64*72];   // XT[p][l] = x[l][p]
    __shared__ unsigned short BT[64*72];   // BT[n][l] = B[l][n]*dec[l]*dt[l]
    __shared__ float dt_sh[64], acs_sh[64], w_sh[64];
    const int tid = threadIdx.x;
    const size_t row0 = (size_t)(c*64)*ZROW;

    if (tid < 64) dt_sh[tid] = dtbuf[(size_t)(c*64+tid)*NH + h];
    __syncthreads();
    if (tid == 0){
        float Ah = -expf(A_log[h]); float s = 0.f;
        for (int l=0;l<64;l++){ s = fmaf(Ah, dt_sh[l], s); acs_sh[l] = s; }
    }
    __syncthreads();
    const float a63 = acs_sh[63];
    if (tid < 64){
        float a = acs_sh[tid];
        acsbuf[((size_t)c*NH + h)*64 + tid] = a;
        w_sh[tid] = expf(a63 - a) * dt_sh[tid];
    }
    if (tid == 0) csumbuf[(size_t)c*NH + h] = a63;
    __syncthreads();

    {
        const int l  = tid >> 2;
        const int f4 = tid & 3;
        const unsigned short* xr = zxbc + row0 + (size_t)l*ZROW;
        const float w = w_sh[l];
        #pragma unroll
        for (int q=0;q<4;q++){
            int col = f4*4 + q*16;
            uint2 xv = *(const uint2*)(xr + DINNER + h*HD + col);
            uint2 bv = *(const uint2*)(xr + DINNER + DINNER + col);
            XT[(col+0)*72 + l] = (unsigned short)(xv.x & 0xffff);
            XT[(col+1)*72 + l] = (unsigned short)(xv.x >> 16);
            XT[(col+2)*72 + l] = (unsigned short)(xv.y & 0xffff);
            XT[(col+3)*72 + l] = (unsigned short)(xv.y >> 16);
            BT[(col+0)*72 + l] = f2bf(bf2f((unsigned short)(bv.x & 0xffff))*w);
            BT[(col+1)*72 + l] = f2bf(bf2f((unsigned short)(bv.x >> 16))*w);
            BT[(col+2)*72 + l] = f2bf(bf2f((unsigned short)(bv.y & 0xffff))*w);
            BT[(col+3)*72 + l] = f2bf(bf2f((unsigned short)(bv.y >> 16))*w);
        }
    }
    __syncthreads();

    const int wave = tid >> 6, lane = tid & 63;
    const int quad = lane >> 4, l15 = lane & 15;
    f32x4 acc[4];
    #pragma unroll
    for (int j=0;j<4;j++) acc[j] = (f32x4){0.f,0.f,0.f,0.f};
    #pragma unroll
    for (int ks=0;ks<2;ks++){
        bf16x8 af = *(const bf16x8*)&XT[(wave*16 + l15)*72 + ks*32 + quad*8];
        #pragma unroll
        for (int j=0;j<4;j++){
            bf16x8 bf = *(const bf16x8*)&BT[(j*16 + l15)*72 + ks*32 + quad*8];
            acc[j] = __builtin_amdgcn_mfma_f32_16x16x32_bf16(af, bf, acc[j], 0,0,0);
        }
    }
    const size_t sbase = ((size_t)c*NH + h)*4096;
    #pragma unroll
    for (int j=0;j<4;j++)
        #pragma unroll
        for (int r=0;r<4;r++){
            int p = wave*16 + quad*4 + r;
            int n = j*16 + l15;
            locst[sbase + (size_t)p*64 + n] = f2bf(acc[j][r]);
        }
}

// ---------------------------------------------------------------------------
// Inter-chunk scan, in place (loc -> entering), grid (NH, 2, nb).
// ---------------------------------------------------------------------------
__global__ __launch_bounds__(256)
void chunk_scan(unsigned short* __restrict__ states,
                const float* __restrict__ csumbuf,
                const float* __restrict__ init_states)
{
    const int h = blockIdx.x, half = blockIdx.y, b = blockIdx.z;
    __shared__ float cs_sh[64];
    const int tid = threadIdx.x;
    if (tid < 64) cs_sh[tid] = csumbuf[(size_t)(b*64 + tid)*NH + h];
    __syncthreads();
    const int e0 = half*2048 + tid*8;
    float S[8];
    {
        const float4* ip = (const float4*)(init_states + (size_t)h*4096 + e0);
        float4 v0 = ip[0], v1 = ip[1];
        S[0]=v0.x; S[1]=v0.y; S[2]=v0.z; S[3]=v0.w;
        S[4]=v1.x; S[5]=v1.y; S[6]=v1.z; S[7]=v1.w;
    }
    for (int zg=0; zg<8; zg++){
        uint4 L[8];
        #pragma unroll
        for (int k=0;k<8;k++)
            L[k] = *(const uint4*)(states + ((size_t)(b*64 + zg*8+k)*NH + h)*4096 + e0);
        #pragma unroll
        for (int k=0;k<8;k++){
            int z = zg*8 + k;
            float dec = expf(cs_sh[z]);
            uint4 o;
            o.x = (unsigned)f2bf(S[0]) | ((unsigned)f2bf(S[1])<<16);
            o.y = (unsigned)f2bf(S[2]) | ((unsigned)f2bf(S[3])<<16);
            o.z = (unsigned)f2bf(S[4]) | ((unsigned)f2bf(S[5])<<16);
            o.w = (unsigned)f2bf(S[6]) | ((unsigned)f2bf(S[7])<<16);
            *(uint4*)(states + ((size_t)(b*64 + z)*NH + h)*4096 + e0) = o;
            unsigned a[4] = {L[k].x, L[k].y, L[k].z, L[k].w};
            #pragma unroll
            for (int q=0;q<4;q++){
                float lo = bf2f((unsigned short)(a[q]&0xffff));
                float hi = bf2f((unsigned short)(a[q]>>16));
                S[q*2+0] = fmaf(dec, S[q*2+0], lo);
                S[q*2+1] = fmaf(dec, S[q*2+1], hi);
            }
        }
    }
}

// ---------------------------------------------------------------------------
// y_fused: grid (NH, nchunks).  G = C·B^T (MFMA) -> score (mask/decay/dt,
// +D on diag) -> Y = score·x + (ea·C)·S_enter^T, single bf16 write.
// ---------------------------------------------------------------------------
__global__ __launch_bounds__(256)
void y_fused(unsigned short* __restrict__ zxbc,
             const float* __restrict__ dtbuf,
             const unsigned short* __restrict__ entst,
             const float* __restrict__ acsbuf,
             const float* __restrict__ Dvec)
{
    const int h = blockIdx.x, c = blockIdx.y;
    __shared__ unsigned short Cr[64*72];
    __shared__ unsigned short Ce[64*72];
    __shared__ unsigned short Bm[64*72];   // B raw; reused for score
    __shared__ unsigned short XT[64*72];
    __shared__ unsigned short Sv[64*72];
    __shared__ float acs_sh[64], dt_sh[64], ea_sh[64];
    const int tid = threadIdx.x;
    const size_t row0 = (size_t)(c*64)*ZROW;
    const size_t sbase = ((size_t)c*NH + h)*4096;

    if (tid < 64){
        float a = acsbuf[((size_t)c*NH + h)*64 + tid];
        acs_sh[tid] = a;
        ea_sh[tid]  = expf(a);
        dt_sh[tid]  = dtbuf[(size_t)(c*64 + tid)*NH + h];
    }
    __syncthreads();

    {
        const int l  = tid >> 2;
        const int f4 = tid & 3;
        const unsigned short* xr = zxbc + row0 + (size_t)l*ZROW;
        const float el = ea_sh[l];
        #pragma unroll
        for (int q=0;q<4;q++){
            int col = f4*4 + q*16;
            uint2 cv = *(const uint2*)(xr + DINNER + DINNER + DSTATE + col);
            uint2 bv = *(const uint2*)(xr + DINNER + DINNER + col);
            uint2 xv = *(const uint2*)(xr + DINNER + h*HD + col);
            *(uint2*)&Cr[l*72 + col] = cv;
            *(uint2*)&Bm[l*72 + col] = bv;
            unsigned short* ce = &Ce[l*72 + col];
            ce[0] = f2bf(bf2f((unsigned short)(cv.x & 0xffff))*el);
            ce[1] = f2bf(bf2f((unsigned short)(cv.x >> 16))*el);
            ce[2] = f2bf(bf2f((unsigned short)(cv.y & 0xffff))*el);
            ce[3] = f2bf(bf2f((unsigned short)(cv.y >> 16))*el);
            XT[(col+0)*72 + l] = (unsigned short)(xv.x & 0xffff);
            XT[(col+1)*72 + l] = (unsigned short)(xv.x >> 16);
            XT[(col+2)*72 + l] = (unsigned short)(xv.y & 0xffff);
            XT[(col+3)*72 + l] = (unsigned short)(xv.y >> 16);
            *(uint2*)&Sv[l*72 + col] = *(const uint2*)(entst + sbase + (size_t)l*64 + col);
        }
    }
    __syncthreads();

    const int wave = tid >> 6, lane = tid & 63;
    const int quad = lane >> 4, l15 = lane & 15;

    f32x4 g[4];
    #pragma unroll
    for (int j=0;j<4;j++) g[j] = (f32x4){0.f,0.f,0.f,0.f};
    #pragma unroll
    for (int ks=0;ks<2;ks++){
        bf16x8 af = *(const bf16x8*)&Cr[(wave*16 + l15)*72 + ks*32 + quad*8];
        #pragma unroll
        for (int j=0;j<4;j++){
            bf16x8 bf = *(const bf16x8*)&Bm[(j*16 + l15)*72 + ks*32 + quad*8];
            g[j] = __builtin_amdgcn_mfma_f32_16x16x32_bf16(af, bf, g[j], 0,0,0);
        }
    }
    __syncthreads();

    const float Dh = Dvec[h];
    #pragma unroll
    for (int j=0;j<4;j++)
        #pragma unroll
        for (int r=0;r<4;r++){
            int l = wave*16 + quad*4 + r;
            int s = j*16 + l15;
            float v = (s <= l) ? g[j][r]*expf(acs_sh[l]-acs_sh[s])*dt_sh[s] : 0.f;
            if (s == l) v += Dh;
            Bm[l*72 + s] = f2bf(v);
        }
    __syncthreads();

    f32x4 y[4];
    #pragma unroll
    for (int j=0;j<4;j++) y[j] = (f32x4){0.f,0.f,0.f,0.f};
    #pragma unroll
    for (int ks=0;ks<2;ks++){
        bf16x8 a1 = *(const bf16x8*)&Bm[(wave*16 + l15)*72 + ks*32 + quad*8];
        bf16x8 a2 = *(const bf16x8*)&Ce[(wave*16 + l15)*72 + ks*32 + quad*8];
        #pragma unroll
        for (int j=0;j<4;j++){
            bf16x8 b1 = *(const bf16x8*)&XT[(j*16 + l15)*72 + ks*32 + quad*8];
            bf16x8 b2 = *(const bf16x8*)&Sv[(j*16 + l15)*72 + ks*32 + quad*8];
            y[j] = __builtin_amdgcn_mfma_f32_16x16x32_bf16(a1, b1, y[j], 0,0,0);
            y[j] = __builtin_amdgcn_mfma_f32_16x16x32_bf16(a2, b2, y[j], 0,0,0);
        }
    }

    #pragma unroll
    for (int j=0;j<4;j++)
        #pragma unroll
        for (int r=0;r<4;r++){
            int l = wave*16 + quad*4 + r;
            int p = j*16 + l15;
            zxbc[row0 + (size_t)l*ZROW + DINNER + h*HD + p] = f2bf(y[j][r]);
        }
}

// ---------------------------------------------------------------------------
// gate + RMSNorm: y = RMSNorm(Y*silu(z))*w; writes y bf16 over z cols.
// ---------------------------------------------------------------------------
__global__ __launch_bounds__(256)
void gate_norm(unsigned short* __restrict__ zxbc, const float* __restrict__ norm_w)
{
    const int m = blockIdx.x;
    const int tid = threadIdx.x;
    unsigned short* row = zxbc + (size_t)m*ZROW;
    uint4 zv = *(const uint4*)(row + tid*8);
    uint4 yv = *(const uint4*)(row + DINNER + tid*8);
    unsigned zz[4] = {zv.x, zv.y, zv.z, zv.w};
    unsigned yy[4] = {yv.x, yv.y, yv.z, yv.w};
    float g[8];
    float acc = 0.f;
    #pragma unroll
    for (int q=0;q<4;q++){
        float zl = bf2f((unsigned short)(zz[q]&0xffff));
        float zh = bf2f((unsigned short)(zz[q]>>16));
        float yl = bf2f((unsigned short)(yy[q]&0xffff));
        float yh = bf2f((unsigned short)(yy[q]>>16));
        g[q*2+0] = yl * zl * sigm(zl);
        g[q*2+1] = yh * zh * sigm(zh);
        acc += g[q*2]*g[q*2] + g[q*2+1]*g[q*2+1];
    }
    #pragma unroll
    for (int o=32;o>0;o>>=1) acc += __shfl_down(acc, o, 64);
    __shared__ float red[4];
    if ((tid & 63)==0) red[tid>>6] = acc;
    __syncthreads();
    float tot = red[0]+red[1]+red[2]+red[3];
    float scale = rsqrtf(tot * (1.f/2048.f) + 1e-5f);
    const float* nw = norm_w + tid*8;
    float4 w0 = *(const float4*)nw;
    float4 w1 = *(const float4*)(nw+4);
    float Wv[8] = {w0.x,w0.y,w0.z,w0.w,w1.x,w1.y,w1.z,w1.w};
    uint4 ov;
    unsigned ow[4];
    #pragma unroll
    for (int q=0;q<4;q++){
        unsigned short lo = f2bf(g[q*2+0]*scale*Wv[q*2+0]);
        unsigned short hi = f2bf(g[q*2+1]*scale*Wv[q*2+1]);
        ow[q] = (unsigned)lo | ((unsigned)hi<<16);
    }
    ov.x=ow[0]; ov.y=ow[1]; ov.z=ow[2]; ov.w=ow[3];
    *(uint4*)(row + tid*8) = ov;
}

// ---------------------------------------------------------------------------
extern "C" void kernel_launch(void* const* d_in, const int* in_sizes, int n_in,
                              void* d_out, int out_size, void* d_ws, size_t ws_size,
                              hipStream_t stream) {
    const float* u           = (const float*)d_in[0];
    const float* in_proj_w   = (const float*)d_in[1];
    const float* conv_w      = (const float*)d_in[2];
    const float* conv_b      = (const float*)d_in[3];
    const float* init_states = (const float*)d_in[4];
    const float* dt_bias     = (const float*)d_in[5];
    const float* A_log       = (const float*)d_in[6];
    const float* Dv          = (const float*)d_in[7];
    const float* norm_w      = (const float*)d_in[8];
    const float* out_proj_w  = (const float*)d_in[9];
    float* out = (float*)d_out;
    char* wsb = (char*)d_ws;

    // BIG layout (~226 MB): all 4 batches in one pipeline.
    // SMALL layout (~66 MB): per-batch windows (proven envelope).
    const size_t BIG_BYTES = 226197504;
    const bool big = (ws_size >= BIG_BYTES);
    const int nb = big ? BATCH : 1;
    const size_t Mrows = (size_t)nb * LSEQ;          // rows per pipeline pass

    size_t off = 0;
    unsigned short* zxbc    = (unsigned short*)(wsb + off); off += Mrows*ZROW*2;
    unsigned short* statesz = (unsigned short*)(wsb + off);
    unsigned short* ubf     = statesz;               // alias: dead before states written
    off += Mrows/64 * NH*HD*DSTATE*2;                // nb*16.78MB
    unsigned short* wibf    = (unsigned short*)(wsb + off); off += (size_t)NPROJ*DMODEL*2;
    unsigned short* woutbf  = (unsigned short*)(wsb + off); off += (size_t)DMODEL*DINNER*2;
    float*          dtbuf   = (float*)(wsb + off);   off += Mrows*NH*4;
    float*          acsbuf  = (float*)(wsb + off);   off += Mrows/64 * NH*64*4;
    float*          csumbuf = (float*)(wsb + off);   off += Mrows/64 * NH*4;
    unsigned short* halo    = (unsigned short*)(wsb + off); off += Mrows/64 * 3*CONVD*2;

    // weights -> bf16 (once; wibf rows 4256..4351 stay poison, never stored)
    f32_to_bf16<<<dim3((4256*1024/8 + 255)/256), 256, 0, stream>>>(
        in_proj_w, wibf, (size_t)4256*1024);
    f32_to_bf16<<<dim3(1024*2048/8/256), 256, 0, stream>>>(
        out_proj_w, woutbf, (size_t)1024*2048);

    const int npass = big ? 1 : BATCH;
    for (int b=0; b<npass; b++){
        const float* ub   = u   + (size_t)b*LSEQ*DMODEL;
        float*       outb = out + (size_t)b*LSEQ*DMODEL;
        const int mt = (int)(Mrows/128);             // M tiles per pass

        // 0) u -> bf16
        f32_to_bf16<<<dim3(Mrows*DMODEL/8/256), 256, 0, stream>>>(
            ub, ubf, Mrows*DMODEL);
        // 1) merged in_proj (z + xBC + dt) + halo + softplus
        gemm_mfma<1><<<dim3(NPROJ/128, mt), 256, 0, stream>>>(
            ubf, wibf, DMODEL, DMODEL, 0,
            nullptr, zxbc, dtbuf, dt_bias, halo);
        // 2) causal conv + silu in place
        conv_inplace<<<dim3(9, (unsigned)(Mrows/64)), 256, 0, stream>>>(
            zxbc, halo, conv_w, conv_b);
        // 3) local states (MFMA) + acs/csum
        states_intra<<<dim3(NH, (unsigned)(Mrows/64)), 256, 0, stream>>>(
            zxbc, dtbuf, A_log, statesz, acsbuf, csumbuf);
        // 4) inter-chunk scan in place (loc -> entering)
        chunk_scan<<<dim3(NH, 2, nb), 256, 0, stream>>>(
            statesz, csumbuf, init_states);
        // 5) fused Y = Y_diag + Y_off + x*D
        y_fused<<<dim3(NH, (unsigned)(Mrows/64)), 256, 0, stream>>>(
            zxbc, dtbuf, statesz, acsbuf, Dv);
        // 6) gate + RMSNorm -> y bf16 over z cols
        gate_norm<<<dim3((unsigned)Mrows), 256, 0, stream>>>(zxbc, norm_w);
        // 7) out_proj -> out fp32
        gemm_mfma<0><<<dim3(DMODEL/128, mt), 256, 0, stream>>>(
            zxbc, woutbf, DINNER, ZROW, DMODEL,
            outb, nullptr, nullptr, nullptr, nullptr);
    }
}

// Round 7
// 645.928 us; speedup vs baseline: 1.7773x; 1.0243x over previous
//
#include <hip/hip_runtime.h>
#include <math.h>

// Mamba2: D_MODEL=1024, EXPAND=2, HEADDIM=64, NGROUPS=1, D_STATE=64,
// D_CONV=4, CHUNK=64, B=4, L=4096.
// Runtime-adaptive: fully-batched pipeline if ws_size allows (~226 MB),
// else per-batch windowed pipeline (~66 MB).  Same kernels in both modes.
#define BATCH  4
#define LSEQ   4096
#define DMODEL 1024
#define DINNER 2048
#define NH     32
#define HD     64
#define DSTATE 64
#define CONVD  2176      // D_INNER + 2*D_STATE
#define NPROJ  4352      // 34*128: z(2048) | xBC(2176) | dt(32)+pad
#define ZROW   4224      // zxbc row stride: z(2048) | xBC(2176)
#define NCHUNK 64

typedef __attribute__((ext_vector_type(8))) short bf16x8;
typedef __attribute__((ext_vector_type(4))) float f32x4;

__device__ __forceinline__ float sigm(float x){ return 1.f/(1.f+expf(-x)); }

__device__ __forceinline__ unsigned short f2bf(float x){
    unsigned u = __float_as_uint(x);
    unsigned r = (u + 0x7fffu + ((u>>16)&1u)) >> 16;
    return (unsigned short)r;
}
__device__ __forceinline__ float bf2f(unsigned short h){
    return __uint_as_float(((unsigned)h)<<16);
}

// async global (16B/lane) -> LDS (wave-uniform base + lane*16)
__device__ __forceinline__ void gl2lds16(const unsigned short* g, short* l){
    __builtin_amdgcn_global_load_lds(
        (const __attribute__((address_space(1))) unsigned int*)g,
        (__attribute__((address_space(3))) unsigned int*)l, 16, 0, 0);
}

// ---------------------------------------------------------------------------
// f32 -> bf16 streaming convert (n multiple of 8)
// ---------------------------------------------------------------------------
__global__ __launch_bounds__(256)
void f32_to_bf16(const float* __restrict__ in, unsigned short* __restrict__ o, size_t n)
{
    size_t i = ((size_t)blockIdx.x*256 + threadIdx.x)*8;
    if (i >= n) return;
    float4 a = *(const float4*)(in + i);
    float4 b = *(const float4*)(in + i + 4);
    uint4 v;
    v.x = (unsigned)f2bf(a.x) | ((unsigned)f2bf(a.y)<<16);
    v.y = (unsigned)f2bf(a.z) | ((unsigned)f2bf(a.w)<<16);
    v.z = (unsigned)f2bf(b.x) | ((unsigned)f2bf(b.y)<<16);
    v.w = (unsigned)f2bf(b.z) | ((unsigned)f2bf(b.w)<<16);
    *(uint4*)(o + i) = v;
}

// ---------------------------------------------------------------------------
// bf16 MFMA GEMM NT, 128x128 tile, BK=32, 4 waves, 4x4 x mfma 16x16x32.
// 1D grid with grouped swizzle (GM=16 M-tiles share B-tiles in L2):
//   pid -> (mtile, ntile) s.t. consecutive blocks cover 16 M x 1 N, then next N.
// EPI=0: fp32 store to Cf (ldc).  EPI=1: merged in_proj epilogue:
//   tiles 0..15 -> z bf16 into zxbc, 16..32 -> xBC bf16 + conv halo,
//   tile 33 -> softplus dt fp32.
// ---------------------------------------------------------------------------
template<int EPI>
__global__ __launch_bounds__(256)
void gemm_mfma(const unsigned short* __restrict__ A,
               const unsigned short* __restrict__ B,
               int K, int lda, int ldc, int ntiles, int Mrows,
               float* __restrict__ Cf,
               unsigned short* __restrict__ zxbc,
               float* __restrict__ dtout,
               const float* __restrict__ dt_bias,
               unsigned short* __restrict__ halo)
{
    __shared__ short As[128*32];
    __shared__ short Bs[128*32];
    const int tid  = threadIdx.x;
    const int wave = tid >> 6;
    const int lane = tid & 63;

    // grouped swizzle: GM M-tiles per group, N-major within group
    const int GM  = 16;
    const int pid = blockIdx.x;
    const int gsz = GM * ntiles;
    const int grp = pid / gsz;
    const int rem = pid - grp*gsz;
    const int bm  = (grp*GM + (rem & (GM-1))) * 128;
    const int bn  = (rem / GM) * 128;

    const int wr = (wave >> 1) * 64;
    const int wc = (wave & 1) * 64;
    const int quad = lane >> 4;
    const int l15  = lane & 15;

    f32x4 acc[4][4];
    #pragma unroll
    for (int i=0;i<4;i++)
        #pragma unroll
        for (int j=0;j<4;j++)
            acc[i][j] = (f32x4){0.f,0.f,0.f,0.f};

    const int srow = (lane >> 2);
    const int skc  = (lane & 3) * 8;

    for (int k0 = 0; k0 < K; k0 += 32){
        #pragma unroll
        for (int s=0; s<4; s++){
            int t = wave*4 + s;
            int r = (t & 7)*16 + srow;
            if (t < 8)
                gl2lds16(A + (size_t)(bm + r)*lda + k0 + skc, &As[(t & 7)*512]);
            else
                gl2lds16(B + (size_t)(bn + r)*K + k0 + skc, &Bs[(t & 7)*512]);
        }
        __syncthreads();
        bf16x8 af[4], bg[4];
        #pragma unroll
        for (int i=0;i<4;i++)
            af[i] = *(const bf16x8*)&As[(wr + i*16 + l15)*32 + quad*8];
        #pragma unroll
        for (int j=0;j<4;j++)
            bg[j] = *(const bf16x8*)&Bs[(wc + j*16 + l15)*32 + quad*8];
        #pragma unroll
        for (int i=0;i<4;i++)
            #pragma unroll
            for (int j=0;j<4;j++)
                acc[i][j] = __builtin_amdgcn_mfma_f32_16x16x32_bf16(af[i], bg[j], acc[i][j], 0,0,0);
        __syncthreads();
    }

    // C/D layout: col = lane&15, row = quad*4 + reg   [m89-verified]
    if (EPI == 0){
        #pragma unroll
        for (int i=0;i<4;i++)
            #pragma unroll
            for (int j=0;j<4;j++){
                int col = bn + wc + j*16 + l15;
                #pragma unroll
                for (int r=0;r<4;r++){
                    int row = bm + wr + i*16 + quad*4 + r;
                    Cf[(size_t)row*ldc + col] = acc[i][j][r];
                }
            }
    } else {
        if (bn < DINNER){
            #pragma unroll
            for (int i=0;i<4;i++)
                #pragma unroll
                for (int r=0;r<4;r++){
                    int row = bm + wr + i*16 + quad*4 + r;
                    #pragma unroll
                    for (int j=0;j<4;j++){
                        int col = bn + wc + j*16 + l15;
                        zxbc[(size_t)row*ZROW + col] = f2bf(acc[i][j][r]);
                    }
                }
        } else if (bn < DINNER + CONVD){
            #pragma unroll
            for (int i=0;i<4;i++)
                #pragma unroll
                for (int r=0;r<4;r++){
                    int row = bm + wr + i*16 + quad*4 + r;
                    int rel = row & 63;
                    int seg = (row >> 6) + 1;
                    #pragma unroll
                    for (int j=0;j<4;j++){
                        int col = bn + wc + j*16 + l15;
                        unsigned short v = f2bf(acc[i][j][r]);
                        zxbc[(size_t)row*ZROW + col] = v;
                        if (rel >= 61 && seg*64 < Mrows)
                            halo[((size_t)(seg*3 + (rel-61)))*CONVD + (col - DINNER)] = v;
                    }
                }
        } else if (wc == 0){
            #pragma unroll
            for (int j=0;j<2;j++){
                int h = j*16 + l15;
                #pragma unroll
                for (int i=0;i<4;i++)
                    #pragma unroll
                    for (int r=0;r<4;r++){
                        int row = bm + wr + i*16 + quad*4 + r;
                        float t = acc[i][j][r] + dt_bias[h];
                        dtout[(size_t)row*NH + h] = (t > 20.f) ? t : log1pf(expf(t));
                    }
            }
        }
    }
}

// ---------------------------------------------------------------------------
// Causal conv(4) + bias + SiLU, in place, bf16.  grid (9, 64*nb); seg is the
// GLOBAL 64-row segment; batch boundaries (seg&63==0) use zero history.
// ---------------------------------------------------------------------------
__global__ __launch_bounds__(256)
void conv_inplace(unsigned short* __restrict__ zxbc,
                  const unsigned short* __restrict__ halo,
                  const float* __restrict__ conv_w, const float* __restrict__ conv_b)
{
    int c = blockIdx.x*256 + threadIdx.x;
    if (c >= CONVD) return;
    int seg = blockIdx.y;
    const float w0=conv_w[c*4+0], w1=conv_w[c*4+1], w2=conv_w[c*4+2], w3=conv_w[c*4+3];
    const float bias = conv_b[c];
    float x0=0.f, x1=0.f, x2=0.f;
    if ((seg & 63) != 0){
        const unsigned short* hp = halo + (size_t)(seg*3)*CONVD + c;
        x0 = bf2f(hp[0]); x1 = bf2f(hp[CONVD]); x2 = bf2f(hp[2*CONVD]);
    }
    unsigned short* p = zxbc + (size_t)(seg*64)*ZROW + DINNER + c;
    for (int i=0;i<64;i++){
        float x3 = bf2f(*p);
        float v = fmaf(w0,x0,fmaf(w1,x1,fmaf(w2,x2,fmaf(w3,x3,bias))));
        *p = f2bf(v * sigm(v));
        x0=x1; x1=x2; x2=x3; p += ZROW;
    }
}

// ---------------------------------------------------------------------------
// states_intra: grid (NH, nchunks) [h fastest -> L2 reuse of B/x rows].
// loc_state[p][n] = sum_l x[l][p]*dt[l]*dec[l]*B[l][n] via NT MFMA.
// ---------------------------------------------------------------------------
__global__ __launch_bounds__(256)
void states_intra(const unsigned short* __restrict__ zxbc,
                  const float* __restrict__ dtbuf,
                  const float* __restrict__ A_log,
                  unsigned short* __restrict__ locst,
                  float* __restrict__ acsbuf,
                  float* __restrict__ csumbuf)
{
    const int h = blockIdx.x, c = blockIdx.y;
    __shared__ unsigned short XT[64*72];   // XT[p][l] = x[l][p]
    __shared__ unsigned short BT[64*72];   // BT[n][l] = B[l][n]*dec[l]*dt[l]
    __shared__ float dt_sh[64], acs_sh[64], w_sh[64];
    const int tid = threadIdx.x;
    const size_t row0 = (size_t)(c*64)*ZROW;

    if (tid < 64) dt_sh[tid] = dtbuf[(size_t)(c*64+tid)*NH + h];
    __syncthreads();
    if (tid == 0){
        float Ah = -expf(A_log[h]); float s = 0.f;
        for (int l=0;l<64;l++){ s = fmaf(Ah, dt_sh[l], s); acs_sh[l] = s; }
    }
    __syncthreads();
    const float a63 = acs_sh[63];
    if (tid < 64){
        float a = acs_sh[tid];
        acsbuf[((size_t)c*NH + h)*64 + tid] = a;
        w_sh[tid] = expf(a63 - a) * dt_sh[tid];
    }
    if (tid == 0) csumbuf[(size_t)c*NH + h] = a63;
    __syncthreads();

    {
        const int l  = tid >> 2;
        const int f4 = tid & 3;
        const unsigned short* xr = zxbc + row0 + (size_t)l*ZROW;
        const float w = w_sh[l];
        #pragma unroll
        for (int q=0;q<4;q++){
            int col = f4*4 + q*16;
            uint2 xv = *(const uint2*)(xr + DINNER + h*HD + col);
            uint2 bv = *(const uint2*)(xr + DINNER + DINNER + col);
            XT[(col+0)*72 + l] = (unsigned short)(xv.x & 0xffff);
            XT[(col+1)*72 + l] = (unsigned short)(xv.x >> 16);
            XT[(col+2)*72 + l] = (unsigned short)(xv.y & 0xffff);
            XT[(col+3)*72 + l] = (unsigned short)(xv.y >> 16);
            BT[(col+0)*72 + l] = f2bf(bf2f((unsigned short)(bv.x & 0xffff))*w);
            BT[(col+1)*72 + l] = f2bf(bf2f((unsigned short)(bv.x >> 16))*w);
            BT[(col+2)*72 + l] = f2bf(bf2f((unsigned short)(bv.y & 0xffff))*w);
            BT[(col+3)*72 + l] = f2bf(bf2f((unsigned short)(bv.y >> 16))*w);
        }
    }
    __syncthreads();

    const int wave = tid >> 6, lane = tid & 63;
    const int quad = lane >> 4, l15 = lane & 15;
    f32x4 acc[4];
    #pragma unroll
    for (int j=0;j<4;j++) acc[j] = (f32x4){0.f,0.f,0.f,0.f};
    #pragma unroll
    for (int ks=0;ks<2;ks++){
        bf16x8 af = *(const bf16x8*)&XT[(wave*16 + l15)*72 + ks*32 + quad*8];
        #pragma unroll
        for (int j=0;j<4;j++){
            bf16x8 bf = *(const bf16x8*)&BT[(j*16 + l15)*72 + ks*32 + quad*8];
            acc[j] = __builtin_amdgcn_mfma_f32_16x16x32_bf16(af, bf, acc[j], 0,0,0);
        }
    }
    const size_t sbase = ((size_t)c*NH + h)*4096;
    #pragma unroll
    for (int j=0;j<4;j++)
        #pragma unroll
        for (int r=0;r<4;r++){
            int p = wave*16 + quad*4 + r;
            int n = j*16 + l15;
            locst[sbase + (size_t)p*64 + n] = f2bf(acc[j][r]);
        }
}

// ---------------------------------------------------------------------------
// Inter-chunk scan, in place (loc -> entering), grid (NH, 2, nb).
// ---------------------------------------------------------------------------
__global__ __launch_bounds__(256)
void chunk_scan(unsigned short* __restrict__ states,
                const float* __restrict__ csumbuf,
                const float* __restrict__ init_states)
{
    const int h = blockIdx.x, half = blockIdx.y, b = blockIdx.z;
    __shared__ float cs_sh[64];
    const int tid = threadIdx.x;
    if (tid < 64) cs_sh[tid] = csumbuf[(size_t)(b*64 + tid)*NH + h];
    __syncthreads();
    const int e0 = half*2048 + tid*8;
    float S[8];
    {
        const float4* ip = (const float4*)(init_states + (size_t)h*4096 + e0);
        float4 v0 = ip[0], v1 = ip[1];
        S[0]=v0.x; S[1]=v0.y; S[2]=v0.z; S[3]=v0.w;
        S[4]=v1.x; S[5]=v1.y; S[6]=v1.z; S[7]=v1.w;
    }
    for (int zg=0; zg<8; zg++){
        uint4 L[8];
        #pragma unroll
        for (int k=0;k<8;k++)
            L[k] = *(const uint4*)(states + ((size_t)(b*64 + zg*8+k)*NH + h)*4096 + e0);
        #pragma unroll
        for (int k=0;k<8;k++){
            int z = zg*8 + k;
            float dec = expf(cs_sh[z]);
            uint4 o;
            o.x = (unsigned)f2bf(S[0]) | ((unsigned)f2bf(S[1])<<16);
            o.y = (unsigned)f2bf(S[2]) | ((unsigned)f2bf(S[3])<<16);
            o.z = (unsigned)f2bf(S[4]) | ((unsigned)f2bf(S[5])<<16);
            o.w = (unsigned)f2bf(S[6]) | ((unsigned)f2bf(S[7])<<16);
            *(uint4*)(states + ((size_t)(b*64 + z)*NH + h)*4096 + e0) = o;
            unsigned a[4] = {L[k].x, L[k].y, L[k].z, L[k].w};
            #pragma unroll
            for (int q=0;q<4;q++){
                float lo = bf2f((unsigned short)(a[q]&0xffff));
                float hi = bf2f((unsigned short)(a[q]>>16));
                S[q*2+0] = fmaf(dec, S[q*2+0], lo);
                S[q*2+1] = fmaf(dec, S[q*2+1], hi);
            }
        }
    }
}

// ---------------------------------------------------------------------------
// y_fused: grid (NH, nchunks).  G = C·B^T (MFMA) -> score (mask/decay/dt,
// +D on diag) -> Y = score·x + (ea·C)·S_enter^T, single bf16 write.
// ---------------------------------------------------------------------------
__global__ __launch_bounds__(256)
void y_fused(unsigned short* __restrict__ zxbc,
             const float* __restrict__ dtbuf,
             const unsigned short* __restrict__ entst,
             const float* __restrict__ acsbuf,
             const float* __restrict__ Dvec)
{
    const int h = blockIdx.x, c = blockIdx.y;
    __shared__ unsigned short Cr[64*72];
    __shared__ unsigned short Ce[64*72];
    __shared__ unsigned short Bm[64*72];   // B raw; reused for score
    __shared__ unsigned short XT[64*72];
    __shared__ unsigned short Sv[64*72];
    __shared__ float acs_sh[64], dt_sh[64], ea_sh[64];
    const int tid = threadIdx.x;
    const size_t row0 = (size_t)(c*64)*ZROW;
    const size_t sbase = ((size_t)c*NH + h)*4096;

    if (tid < 64){
        float a = acsbuf[((size_t)c*NH + h)*64 + tid];
        acs_sh[tid] = a;
        ea_sh[tid]  = expf(a);
        dt_sh[tid]  = dtbuf[(size_t)(c*64 + tid)*NH + h];
    }
    __syncthreads();

    {
        const int l  = tid >> 2;
        const int f4 = tid & 3;
        const unsigned short* xr = zxbc + row0 + (size_t)l*ZROW;
        const float el = ea_sh[l];
        #pragma unroll
        for (int q=0;q<4;q++){
            int col = f4*4 + q*16;
            uint2 cv = *(const uint2*)(xr + DINNER + DINNER + DSTATE + col);
            uint2 bv = *(const uint2*)(xr + DINNER + DINNER + col);
            uint2 xv = *(const uint2*)(xr + DINNER + h*HD + col);
            *(uint2*)&Cr[l*72 + col] = cv;
            *(uint2*)&Bm[l*72 + col] = bv;
            unsigned short* ce = &Ce[l*72 + col];
            ce[0] = f2bf(bf2f((unsigned short)(cv.x & 0xffff))*el);
            ce[1] = f2bf(bf2f((unsigned short)(cv.x >> 16))*el);
            ce[2] = f2bf(bf2f((unsigned short)(cv.y & 0xffff))*el);
            ce[3] = f2bf(bf2f((unsigned short)(cv.y >> 16))*el);
            XT[(col+0)*72 + l] = (unsigned short)(xv.x & 0xffff);
            XT[(col+1)*72 + l] = (unsigned short)(xv.x >> 16);
            XT[(col+2)*72 + l] = (unsigned short)(xv.y & 0xffff);
            XT[(col+3)*72 + l] = (unsigned short)(xv.y >> 16);
            *(uint2*)&Sv[l*72 + col] = *(const uint2*)(entst + sbase + (size_t)l*64 + col);
        }
    }
    __syncthreads();

    const int wave = tid >> 6, lane = tid & 63;
    const int quad = lane >> 4, l15 = lane & 15;

    f32x4 g[4];
    #pragma unroll
    for (int j=0;j<4;j++) g[j] = (f32x4){0.f,0.f,0.f,0.f};
    #pragma unroll
    for (int ks=0;ks<2;ks++){
        bf16x8 af = *(const bf16x8*)&Cr[(wave*16 + l15)*72 + ks*32 + quad*8];
        #pragma unroll
        for (int j=0;j<4;j++){
            bf16x8 bf = *(const bf16x8*)&Bm[(j*16 + l15)*72 + ks*32 + quad*8];
            g[j] = __builtin_amdgcn_mfma_f32_16x16x32_bf16(af, bf, g[j], 0,0,0);
        }
    }
    __syncthreads();

    const float Dh = Dvec[h];
    #pragma unroll
    for (int j=0;j<4;j++)
        #pragma unroll
        for (int r=0;r<4;r++){
            int l = wave*16 + quad*4 + r;
            int s = j*16 + l15;
            float v = (s <= l) ? g[j][r]*expf(acs_sh[l]-acs_sh[s])*dt_sh[s] : 0.f;
            if (s == l) v += Dh;
            Bm[l*72 + s] = f2bf(v);
        }
    __syncthreads();

    f32x4 y[4];
    #pragma unroll
    for (int j=0;j<4;j++) y[j] = (f32x4){0.f,0.f,0.f,0.f};
    #pragma unroll
    for (int ks=0;ks<2;ks++){
        bf16x8 a1 = *(const bf16x8*)&Bm[(wave*16 + l15)*72 + ks*32 + quad*8];
        bf16x8 a2 = *(const bf16x8*)&Ce[(wave*16 + l15)*72 + ks*32 + quad*8];
        #pragma unroll
        for (int j=0;j<4;j++){
            bf16x8 b1 = *(const bf16x8*)&XT[(j*16 + l15)*72 + ks*32 + quad*8];
            bf16x8 b2 = *(const bf16x8*)&Sv[(j*16 + l15)*72 + ks*32 + quad*8];
            y[j] = __builtin_amdgcn_mfma_f32_16x16x32_bf16(a1, b1, y[j], 0,0,0);
            y[j] = __builtin_amdgcn_mfma_f32_16x16x32_bf16(a2, b2, y[j], 0,0,0);
        }
    }

    #pragma unroll
    for (int j=0;j<4;j++)
        #pragma unroll
        for (int r=0;r<4;r++){
            int l = wave*16 + quad*4 + r;
            int p = j*16 + l15;
            zxbc[row0 + (size_t)l*ZROW + DINNER + h*HD + p] = f2bf(y[j][r]);
        }
}

// ---------------------------------------------------------------------------
// gate + RMSNorm: y = RMSNorm(Y*silu(z))*w; writes y bf16 over z cols.
// ---------------------------------------------------------------------------
__global__ __launch_bounds__(256)
void gate_norm(unsigned short* __restrict__ zxbc, const float* __restrict__ norm_w)
{
    const int m = blockIdx.x;
    const int tid = threadIdx.x;
    unsigned short* row = zxbc + (size_t)m*ZROW;
    uint4 zv = *(const uint4*)(row + tid*8);
    uint4 yv = *(const uint4*)(row + DINNER + tid*8);
    unsigned zz[4] = {zv.x, zv.y, zv.z, zv.w};
    unsigned yy[4] = {yv.x, yv.y, yv.z, yv.w};
    float g[8];
    float acc = 0.f;
    #pragma unroll
    for (int q=0;q<4;q++){
        float zl = bf2f((unsigned short)(zz[q]&0xffff));
        float zh = bf2f((unsigned short)(zz[q]>>16));
        float yl = bf2f((unsigned short)(yy[q]&0xffff));
        float yh = bf2f((unsigned short)(yy[q]>>16));
        g[q*2+0] = yl * zl * sigm(zl);
        g[q*2+1] = yh * zh * sigm(zh);
        acc += g[q*2]*g[q*2] + g[q*2+1]*g[q*2+1];
    }
    #pragma unroll
    for (int o=32;o>0;o>>=1) acc += __shfl_down(acc, o, 64);
    __shared__ float red[4];
    if ((tid & 63)==0) red[tid>>6] = acc;
    __syncthreads();
    float tot = red[0]+red[1]+red[2]+red[3];
    float scale = rsqrtf(tot * (1.f/2048.f) + 1e-5f);
    const float* nw = norm_w + tid*8;
    float4 w0 = *(const float4*)nw;
    float4 w1 = *(const float4*)(nw+4);
    float Wv[8] = {w0.x,w0.y,w0.z,w0.w,w1.x,w1.y,w1.z,w1.w};
    uint4 ov;
    unsigned ow[4];
    #pragma unroll
    for (int q=0;q<4;q++){
        unsigned short lo = f2bf(g[q*2+0]*scale*Wv[q*2+0]);
        unsigned short hi = f2bf(g[q*2+1]*scale*Wv[q*2+1]);
        ow[q] = (unsigned)lo | ((unsigned)hi<<16);
    }
    ov.x=ow[0]; ov.y=ow[1]; ov.z=ow[2]; ov.w=ow[3];
    *(uint4*)(row + tid*8) = ov;
}

// ---------------------------------------------------------------------------
extern "C" void kernel_launch(void* const* d_in, const int* in_sizes, int n_in,
                              void* d_out, int out_size, void* d_ws, size_t ws_size,
                              hipStream_t stream) {
    const float* u           = (const float*)d_in[0];
    const float* in_proj_w   = (const float*)d_in[1];
    const float* conv_w      = (const float*)d_in[2];
    const float* conv_b      = (const float*)d_in[3];
    const float* init_states = (const float*)d_in[4];
    const float* dt_bias     = (const float*)d_in[5];
    const float* A_log       = (const float*)d_in[6];
    const float* Dv          = (const float*)d_in[7];
    const float* norm_w      = (const float*)d_in[8];
    const float* out_proj_w  = (const float*)d_in[9];
    float* out = (float*)d_out;
    char* wsb = (char*)d_ws;

    // BIG layout (~226 MB): all 4 batches in one pipeline.
    // SMALL layout (~66 MB): per-batch windows (proven envelope).
    const size_t BIG_BYTES = 226197504;
    const bool big = (ws_size >= BIG_BYTES);
    const int nb = big ? BATCH : 1;
    const size_t Mrows = (size_t)nb * LSEQ;          // rows per pipeline pass

    size_t off = 0;
    unsigned short* zxbc    = (unsigned short*)(wsb + off); off += Mrows*ZROW*2;
    unsigned short* statesz = (unsigned short*)(wsb + off);
    unsigned short* ubf     = statesz;               // alias: dead before states written
    off += Mrows/64 * NH*HD*DSTATE*2;                // nb*16.78MB
    unsigned short* wibf    = (unsigned short*)(wsb + off); off += (size_t)NPROJ*DMODEL*2;
    unsigned short* woutbf  = (unsigned short*)(wsb + off); off += (size_t)DMODEL*DINNER*2;
    float*          dtbuf   = (float*)(wsb + off);   off += Mrows*NH*4;
    float*          acsbuf  = (float*)(wsb + off);   off += Mrows/64 * NH*64*4;
    float*          csumbuf = (float*)(wsb + off);   off += Mrows/64 * NH*4;
    unsigned short* halo    = (unsigned short*)(wsb + off); off += Mrows/64 * 3*CONVD*2;

    // weights -> bf16 (once; wibf rows 4256..4351 stay poison, never stored)
    f32_to_bf16<<<dim3((4256*1024/8 + 255)/256), 256, 0, stream>>>(
        in_proj_w, wibf, (size_t)4256*1024);
    f32_to_bf16<<<dim3(1024*2048/8/256), 256, 0, stream>>>(
        out_proj_w, woutbf, (size_t)1024*2048);

    const int npass = big ? 1 : BATCH;
    for (int b=0; b<npass; b++){
        const float* ub   = u   + (size_t)b*LSEQ*DMODEL;
        float*       outb = out + (size_t)b*LSEQ*DMODEL;
        const int mt = (int)(Mrows/128);             // M tiles per pass

        // 0) u -> bf16
        f32_to_bf16<<<dim3(Mrows*DMODEL/8/256), 256, 0, stream>>>(
            ub, ubf, Mrows*DMODEL);
        // 1) merged in_proj (z + xBC + dt) + halo + softplus, grouped swizzle
        gemm_mfma<1><<<dim3((NPROJ/128) * mt), 256, 0, stream>>>(
            ubf, wibf, DMODEL, DMODEL, 0, NPROJ/128, (int)Mrows,
            nullptr, zxbc, dtbuf, dt_bias, halo);
        // 2) causal conv + silu in place
        conv_inplace<<<dim3(9, (unsigned)(Mrows/64)), 256, 0, stream>>>(
            zxbc, halo, conv_w, conv_b);
        // 3) local states (MFMA) + acs/csum
        states_intra<<<dim3(NH, (unsigned)(Mrows/64)), 256, 0, stream>>>(
            zxbc, dtbuf, A_log, statesz, acsbuf, csumbuf);
        // 4) inter-chunk scan in place (loc -> entering)
        chunk_scan<<<dim3(NH, 2, nb), 256, 0, stream>>>(
            statesz, csumbuf, init_states);
        // 5) fused Y = Y_diag + Y_off + x*D
        y_fused<<<dim3(NH, (unsigned)(Mrows/64)), 256, 0, stream>>>(
            zxbc, dtbuf, statesz, acsbuf, Dv);
        // 6) gate + RMSNorm -> y bf16 over z cols
        gate_norm<<<dim3((unsigned)Mrows), 256, 0, stream>>>(zxbc, norm_w);
        // 7) out_proj -> out fp32, grouped swizzle
        gemm_mfma<0><<<dim3((DMODEL/128) * mt), 256, 0, stream>>>(
            zxbc, woutbf, DINNER, ZROW, DMODEL, DMODEL/128, (int)Mrows,
            outb, nullptr, nullptr, nullptr, nullptr);
    }
}